// Round 9
// baseline (344.889 us; speedup 1.0000x reference)
//
#include <hip/hip_runtime.h>
#include <cstdint>
#include <cstddef>

#define T_SEQ 2048
#define DMODEL 2048
#define HQ 16
#define HKV 4
#define HD 128

typedef __attribute__((ext_vector_type(4))) float f32x4;
typedef __attribute__((ext_vector_type(8))) short bf16x8;
typedef __attribute__((ext_vector_type(4))) short short4v;
typedef __attribute__((ext_vector_type(2))) short short2v;
typedef __attribute__((ext_vector_type(4))) unsigned uint4v;

__device__ __forceinline__ short f2bf(float f) {
  unsigned u = __builtin_bit_cast(unsigned, f);
  u = (u + 0x7FFFu + ((u >> 16) & 1u)) >> 16;
  return (short)u;
}
__device__ __forceinline__ float bf2f(short s) {
  unsigned u = ((unsigned)(unsigned short)s) << 16;
  return __builtin_bit_cast(float, u);
}
// pack hi16(a) | hi16(b)<<16 (bf16 truncation) in ONE v_perm_b32
__device__ __forceinline__ unsigned pk_hi16(float a, float b) {
  return __builtin_amdgcn_perm(__builtin_bit_cast(unsigned, b),
                               __builtin_bit_cast(unsigned, a), 0x07060302u);
}

__device__ __forceinline__ void g2lds16(const void* g, void* l) {
  __builtin_amdgcn_global_load_lds(
      (const __attribute__((address_space(1))) void*)g,
      (__attribute__((address_space(3))) void*)l, 16, 0, 0);
}

// ---------------- convert f32 -> bf16 ----------------
__global__ void cvt_kernel(const float* __restrict__ src, short* __restrict__ dst, int n) {
  int idx = blockIdx.x * 256 + threadIdx.x;
  int i = idx * 4;
  if (i >= n) return;
  float4 v = *(const float4*)(src + i);
  short4v o;
  o[0] = f2bf(v.x); o[1] = f2bf(v.y); o[2] = f2bf(v.z); o[3] = f2bf(v.w);
  *(short4v*)(dst + i) = o;
}

// ---------------- transpose + convert: src [R][C] f32 -> dst [C][R] bf16 ----------------
__global__ void transpose_cvt(const float* __restrict__ src, short* __restrict__ dst, int R, int C) {
  __shared__ float tile[32][33];
  int c0 = blockIdx.x * 32, r0 = blockIdx.y * 32;
  int tx = threadIdx.x, ty = threadIdx.y;
  #pragma unroll
  for (int i = 0; i < 32; i += 8)
    tile[ty + i][tx] = src[(size_t)(r0 + ty + i) * C + c0 + tx];
  __syncthreads();
  #pragma unroll
  for (int i = 0; i < 32; i += 8)
    dst[(size_t)(c0 + ty + i) * R + r0 + tx] = f2bf(tile[tx][ty + i]);
}

// ---------------- GEMM: C = A[M][K] * B[K][N], BT is B transposed [N][K] ----------------
template <int MODE>
__global__ __launch_bounds__(256, 2) void gemm_kernel(
    const short* __restrict__ A, const short* __restrict__ BT,
    void* __restrict__ C0, void* __restrict__ C1, void* __restrict__ C2,
    int M, int N, int K)
{
  __shared__ short As[128 * 32];
  __shared__ short Bs[128 * 32];
  const int tid = threadIdx.x;
  const int lane = tid & 63, w = tid >> 6;
  const int l15 = lane & 15, g = lane >> 4;
  const int m0 = blockIdx.y * 128, n0 = blockIdx.x * 128;
  const int wm = (w >> 1) * 64, wn = (w & 1) * 64;

  f32x4 acc[4][4] = {};

  for (int k0 = 0; k0 < K; k0 += 32) {
    __syncthreads();
    #pragma unroll
    for (int call = 0; call < 2; call++) {
      int tau = call * 256 + tid;
      int row = tau >> 2, c = tau & 3;
      int swz = (row & 3) ^ ((row >> 2) & 3);
      g2lds16(A + (size_t)(m0 + row) * K + k0 + ((c ^ swz) << 3),
              (char*)As + call * 4096 + w * 1024);
      g2lds16(BT + (size_t)(n0 + row) * K + k0 + ((c ^ swz) << 3),
              (char*)Bs + call * 4096 + w * 1024);
    }
    __syncthreads();
    bf16x8 af[4], bfr[4];
    #pragma unroll
    for (int mi = 0; mi < 4; mi++) {
      int row = wm + mi * 16 + l15;
      int ch = g ^ ((row & 3) ^ ((row >> 2) & 3));
      af[mi] = *(const bf16x8*)(As + row * 32 + ch * 8);
    }
    #pragma unroll
    for (int ni = 0; ni < 4; ni++) {
      int row = wn + ni * 16 + l15;
      int ch = g ^ ((row & 3) ^ ((row >> 2) & 3));
      bfr[ni] = *(const bf16x8*)(Bs + row * 32 + ch * 8);
    }
    #pragma unroll
    for (int mi = 0; mi < 4; mi++)
      #pragma unroll
      for (int ni = 0; ni < 4; ni++)
        acc[mi][ni] = __builtin_amdgcn_mfma_f32_16x16x32_bf16(af[mi], bfr[ni], acc[mi][ni], 0, 0, 0);
  }

  if (MODE == 1) {
    float* C = (float*)C0;
    #pragma unroll
    for (int mi = 0; mi < 4; mi++)
      #pragma unroll
      for (int r = 0; r < 4; r++) {
        int m = m0 + wm + mi * 16 + g * 4 + r;
        #pragma unroll
        for (int ni = 0; ni < 4; ni++)
          C[(size_t)m * N + n0 + wn + ni * 16 + l15] = acc[mi][ni][r];
      }
  } else {
    short* Cb; int ldc, nc;
    if (MODE == 0) { Cb = (short*)C0; ldc = N; nc = n0; }
    else {
      if (n0 < 2048)      { Cb = (short*)C0; ldc = 2048; nc = n0; }
      else if (n0 < 2560) { Cb = (short*)C1; ldc = 512;  nc = n0 - 2048; }
      else                { Cb = (short*)C2; ldc = 512;  nc = n0 - 2560; }
    }
    #pragma unroll
    for (int mi = 0; mi < 4; mi++)
      #pragma unroll
      for (int r = 0; r < 4; r++) {
        int m = m0 + wm + mi * 16 + g * 4 + r;
        #pragma unroll
        for (int ni = 0; ni < 4; ni++)
          Cb[(size_t)m * ldc + nc + wn + ni * 16 + l15] = f2bf(acc[mi][ni][r]);
      }
  }
}

// ---------------- RoPE in-place on [B*T][NH][128] bf16 ----------------
__global__ void rope_kernel(short* __restrict__ buf, int NH, float scale, int npairs) {
  int idx = blockIdx.x * 256 + threadIdx.x;
  if (idx >= npairs) return;
  int i = idx & 63;
  int th = idx >> 6;
  int t = (th / NH) % T_SEQ;
  size_t base = (size_t)th * 128;
  float invf = exp2f(-(float)i * 0.20762050593046014f);
  float theta = (float)t * invf;
  float sn, cs;
  sincosf(theta, &sn, &cs);
  float a = bf2f(buf[base + i]);
  float b = bf2f(buf[base + 64 + i]);
  buf[base + i]      = f2bf((a * cs - b * sn) * scale);
  buf[base + 64 + i] = f2bf((b * cs + a * sn) * scale);
}

// ---------------- Flash attention (causal, GQA), swapped-operand MFMA ----------------
// 256 thr / 4 waves, 32 q-rows per wave (qc=2 subtiles) -> K/V LDS fragments
// amortized over 2x the q-rows (LDS-BW bound fix). __launch_bounds__(256,3):
// 3 blocks/CU (144 KB LDS, VGPR cap 170 - no spill at ~130). Grid 768 = exactly
// full residency. qti>=8 blocks split kv 2-way (interleaved tiles) -> partials.
__global__ __launch_bounds__(256, 3) void attn_kernel(
    const short* __restrict__ qg, const short* __restrict__ kg,
    const short* __restrict__ vg, short* __restrict__ og,
    short* __restrict__ pOn, float2* __restrict__ ml)
{
  __shared__ short Ks[2][64 * 128];  // 32 KB
  __shared__ short Vt[128 * 64];     // 16 KB
  const int tid = threadIdx.x;
  const int lane = tid & 63, w = tid >> 6;          // 4 waves
  const int l15 = lane & 15, g = lane >> 4;
  const int b = blockIdx.z;
  const int bx = blockIdx.x;                         // 0..23
  const bool split = bx < 16;
  const int qti = split ? (8 + (bx >> 1)) : (bx - 16);
  const int hf = split ? (bx & 1) : 0;
  const int tstep = split ? 2 : 1;
  const int qt0 = qti * 128;
  const int h = blockIdx.y, hk = h >> 2;
  const int qw0 = qt0 + w * 32;                     // 32 q-rows per wave

  // Q fragments: [qc][ks], lane holds Q[q=qw0+qc*16+l15][d=(ks*4+g)*8 ..+7]
  bf16x8 qf[2][4];
  #pragma unroll
  for (int qc = 0; qc < 2; qc++) {
    size_t t = (size_t)b * T_SEQ + qw0 + qc * 16 + l15;
    const short* qp = qg + (t * HQ + h) * HD;
    #pragma unroll
    for (int ks = 0; ks < 4; ks++)
      qf[qc][ks] = *(const bf16x8*)(qp + ks * 32 + g * 8);
  }

  f32x4 of[2][8] = {};               // O^T acc [qc][dc]: d=dc*16+4g+r, q=l15
  float m2[2] = {-INFINITY, -INFINITY};
  float ls[2] = {0.f, 0.f};          // per-lane partials (reduced at epilogue)

  const short* kbase = kg + ((size_t)b * T_SEQ * HKV + hk) * HD;
  const short* vbase = vg + ((size_t)b * T_SEQ * HKV + hk) * HD;
  const int ti = tid & 15;
  const int kv4 = ti * 4, d8s = (tid >> 4) * 8;
  // stored position of kv=4*ti (P k-order); kv4..kv4+3 -> pbase..pbase+3
  const int pbase = (ti >> 3) * 32 + (ti & 3) * 8 + ((ti >> 2) & 1) * 4;
  const int ntAll = 2 * qti + 2;     // kv tiles of 64 (absolute count)

  bf16x8 vr[4];

  auto stageK = [&](int t, int nb) {
    #pragma unroll
    for (int call = 0; call < 4; call++) {
      int tau = call * 256 + tid;
      int kv = tau >> 4, c = tau & 15;
      g2lds16(kbase + (size_t)(t * 64 + kv) * (HKV * HD) + ((c ^ (kv & 7)) << 3),
              (char*)Ks[nb] + call * 4096 + w * 1024);
    }
  };
  auto loadV = [&](int t) {
    #pragma unroll
    for (int i = 0; i < 4; i++)
      vr[i] = *(const bf16x8*)(vbase + (size_t)(t * 64 + kv4 + i) * (HKV * HD) + d8s);
  };
  auto writeV = [&]() {
    #pragma unroll
    for (int e = 0; e < 8; e++) {
      short4v t4;
      t4[0] = vr[0][e]; t4[1] = vr[1][e]; t4[2] = vr[2][e]; t4[3] = vr[3][e];
      *(short4v*)(&Vt[(d8s + e) * 64 + (pbase ^ (e << 3))]) = t4;
    }
  };

  // prologue: first tile (index hf) into buffer 0
  stageK(hf, 0);
  loadV(hf);
  __syncthreads();                    // K staged; vr valid
  writeV();
  __syncthreads();                    // Vt visible

  int buf = 0;
  for (int t = hf; t < ntAll; t += tstep) {
    const int kv0 = t * 64;
    const int tn = t + tstep;
    const bool haveNext = (tn < ntAll);
    if (haveNext) { loadV(tn); stageK(tn, buf ^ 1); }

    if (kv0 <= qw0 + 31) {
      const short* Kc = Ks[buf];
      f32x4 sacc[4][2] = {};
      __builtin_amdgcn_s_setprio(1);
      #pragma unroll
      for (int ks = 0; ks < 4; ks++) {
        bf16x8 kf[4];
        #pragma unroll
        for (int kt = 0; kt < 4; kt++) {
          int row = kt * 16 + l15;
          int ch = (ks * 4 + g) ^ (row & 7);
          kf[kt] = *(const bf16x8*)(Kc + row * 128 + ch * 8);
        }
        #pragma unroll
        for (int kt = 0; kt < 4; kt++)
          #pragma unroll
          for (int qc = 0; qc < 2; qc++)
            sacc[kt][qc] = __builtin_amdgcn_mfma_f32_16x16x32_bf16(kf[kt], qf[qc][ks], sacc[kt][qc], 0, 0, 0);
      }
      __builtin_amdgcn_s_setprio(0);
      const bool needmask = (kv0 + 63) > qw0;
      bf16x8 pb[2][2];                 // [ktw][qc]
      #pragma unroll
      for (int qc = 0; qc < 2; qc++) {
        int qpos = qw0 + qc * 16 + l15;
        float vmax = -INFINITY;
        #pragma unroll
        for (int kt = 0; kt < 4; kt++)
          #pragma unroll
          for (int r = 0; r < 4; r++) {
            int kvpos = kv0 + kt * 16 + g * 4 + r;
            float sv = sacc[kt][qc][r];
            if (needmask && kvpos > qpos) sv = -INFINITY;
            sacc[kt][qc][r] = sv;
            vmax = fmaxf(vmax, sv);
          }
        vmax = fmaxf(vmax, __shfl_xor(vmax, 16));
        vmax = fmaxf(vmax, __shfl_xor(vmax, 32));
        if (!__all(vmax <= m2[qc] + 8.0f)) {   // defer-max (T13)
          float mnew = fmaxf(m2[qc], vmax);
          float resc = exp2f(m2[qc] - mnew);
          m2[qc] = mnew;
          ls[qc] *= resc;                       // per-lane partial; resc row-uniform
          #pragma unroll
          for (int dc = 0; dc < 8; dc++) of[qc][dc] *= resc;
        }
        float mref = m2[qc];
        #pragma unroll
        for (int kt = 0; kt < 4; kt++)
          #pragma unroll
          for (int r = 0; r < 4; r++) {
            float p = exp2f(sacc[kt][qc][r] - mref);
            sacc[kt][qc][r] = p;
            ls[qc] += p;                        // deferred: no per-tile shuffles
          }
        // pack P into stored k-order
        #pragma unroll
        for (int ktw = 0; ktw < 2; ktw++) {
          uint4v pw;
          pw[0] = pk_hi16(sacc[2 * ktw][qc][0], sacc[2 * ktw][qc][1]);
          pw[1] = pk_hi16(sacc[2 * ktw][qc][2], sacc[2 * ktw][qc][3]);
          pw[2] = pk_hi16(sacc[2 * ktw + 1][qc][0], sacc[2 * ktw + 1][qc][1]);
          pw[3] = pk_hi16(sacc[2 * ktw + 1][qc][2], sacc[2 * ktw + 1][qc][3]);
          pb[ktw][qc] = __builtin_bit_cast(bf16x8, pw);
        }
      }
      // O^T += V^T * P : one swizzled ds_read_b128 per fragment, shared by qc pair
      __builtin_amdgcn_s_setprio(1);
      #pragma unroll
      for (int ktw = 0; ktw < 2; ktw++)
        #pragma unroll
        for (int dc = 0; dc < 8; dc++) {
          int row = dc * 16 + l15;
          bf16x8 vf = *(const bf16x8*)(&Vt[row * 64 + ((ktw * 32 + g * 8) ^ ((l15 & 7) << 3))]);
          #pragma unroll
          for (int qc = 0; qc < 2; qc++)
            of[qc][dc] = __builtin_amdgcn_mfma_f32_16x16x32_bf16(vf, pb[ktw][qc], of[qc][dc], 0, 0, 0);
        }
      __builtin_amdgcn_s_setprio(0);
    }

    __syncthreads();                 // reads of Vt/Ks[buf] done; prefetch drained
    if (haveNext) writeV();
    __syncthreads();                 // Vt(next) visible
    buf ^= 1;
  }

  // epilogue: reduce ls across g-lanes, then store
  #pragma unroll
  for (int qc = 0; qc < 2; qc++) {
    float lss = ls[qc];
    lss += __shfl_xor(lss, 16);
    lss += __shfl_xor(lss, 32);
    float inv = 1.0f / lss;
    if (!split) {
      size_t t = (size_t)b * T_SEQ + qw0 + qc * 16 + l15;
      short* op = og + (t * HQ + h) * HD;
      #pragma unroll
      for (int dc = 0; dc < 8; dc++) {
        short4v o;
        #pragma unroll
        for (int r = 0; r < 4; r++) o[r] = f2bf(of[qc][dc][r] * inv);
        *(short4v*)(op + dc * 16 + g * 4) = o;
      }
    } else {
      size_t row = ((size_t)((b * 16 + h) * 2 + hf)) * 1024 + (qw0 - 1024) + qc * 16 + l15;
      short* op = pOn + row * 128;
      #pragma unroll
      for (int dc = 0; dc < 8; dc++) {
        short4v o;
        #pragma unroll
        for (int r = 0; r < 4; r++) o[r] = f2bf(of[qc][dc][r] * inv);
        *(short4v*)(op + dc * 16 + g * 4) = o;
      }
      if (g == 0) {
        float2 st; st.x = m2[qc]; st.y = lss;
        ml[row] = st;
      }
    }
  }
}

// ---------------- combine split-KV partials (q rows 1024..2047) -> ab ----------------
__global__ void combine_kernel(const short* __restrict__ pOn, const float2* __restrict__ ml,
                               short* __restrict__ ab) {
  int idx = blockIdx.x * 256 + threadIdx.x;   // 1,048,576 threads
  int d4 = (idx & 31) * 4;
  int r = idx >> 5;                           // bh*1024 + q'
  int q = r & 1023, bh = r >> 10;             // bh in [0,32)
  size_t row0 = ((size_t)bh * 2) * 1024 + q;
  size_t row1 = row0 + 1024;
  float2 s0 = ml[row0], s1 = ml[row1];
  float M = fmaxf(s0.x, s1.x);
  float w0 = s0.y * exp2f(s0.x - M);
  float w1 = s1.y * exp2f(s1.x - M);
  float inv = 1.0f / (w0 + w1);
  w0 *= inv; w1 *= inv;
  short4v a = *(const short4v*)(pOn + row0 * 128 + d4);
  short4v c = *(const short4v*)(pOn + row1 * 128 + d4);
  short4v o;
  #pragma unroll
  for (int j = 0; j < 4; j++) o[j] = f2bf(w0 * bf2f(a[j]) + w1 * bf2f(c[j]));
  int bb = bh >> 4, hh = bh & 15;
  *(short4v*)(ab + ((size_t)(bb * T_SEQ + 1024 + q) * 16 + hh) * 128 + d4) = o;
}

extern "C" void kernel_launch(void* const* d_in, const int* in_sizes, int n_in,
                              void* d_out, int out_size, void* d_ws, size_t ws_size,
                              hipStream_t stream) {
  (void)in_sizes; (void)n_in; (void)out_size; (void)ws_size;
  const float* x  = (const float*)d_in[0];
  const float* Wq = (const float*)d_in[2];
  const float* Wk = (const float*)d_in[3];
  const float* Wv = (const float*)d_in[4];
  const float* Wo = (const float*)d_in[5];

  char* ws = (char*)d_ws;
  // phase-1 overlays (dead after QKV GEMM):
  short*  xb   = (short*)(ws);                   // [0,16M)
  short*  wall = (short*)(ws + 16777216);        // [16M,29.4M) WqT|WkT|WvT
  short*  wkT  = wall + (size_t)2048 * 2048;
  short*  wvT  = wall + (size_t)2560 * 2048;
  // phase-2 overlays (attn partials; reuse xb/wall space):
  short*  pOn  = (short*)(ws);                   // [0,16M)
  float2* ml   = (float2*)(ws + 16777216);       // [16M,16.5M)
  // persistent:
  short*  woT  = (short*)(ws + 29360128);        // 8 MB
  short*  qb   = (short*)(ws + 37748736);        // 16 MB [B,T,HQ,128]
  short*  kb   = (short*)(ws + 54525952);        // 4 MB  [B,T,HKV,128]
  short*  vb   = (short*)(ws + 58720256);        // 4 MB  [B,T,HKV,128]
  short*  ab   = (short*)(ws + 62914560);        // 16 MB [4096][2048]

  const float MULT = 0.08838834764831845f;
  const float LOG2E = 1.4426950408889634f;
  const float QSCALE = MULT * LOG2E;

  dim3 tb(32, 8);
  cvt_kernel<<<8192, 256, 0, stream>>>(x, xb, 8388608);
  transpose_cvt<<<dim3(64, 64), tb, 0, stream>>>(Wq, wall, 2048, 2048);
  transpose_cvt<<<dim3(16, 64), tb, 0, stream>>>(Wk, wkT, 2048, 512);
  transpose_cvt<<<dim3(16, 64), tb, 0, stream>>>(Wv, wvT, 2048, 512);
  transpose_cvt<<<dim3(64, 64), tb, 0, stream>>>(Wo, woT, 2048, 2048);

  // fused QKV projection: [4096][2048] x [2048][3072] -> qb|kb|vb
  gemm_kernel<2><<<dim3(24, 32), 256, 0, stream>>>(xb, wall, qb, kb, vb, 4096, 3072, 2048);

  rope_kernel<<<16384, 256, 0, stream>>>(qb, HQ, QSCALE, 4194304);
  rope_kernel<<<4096, 256, 0, stream>>>(kb, HKV, 1.0f, 1048576);

  attn_kernel<<<dim3(24, 16, 2), 256, 0, stream>>>(qb, kb, vb, ab, pOn, ml);
  combine_kernel<<<4096, 256, 0, stream>>>(pOn, ml, ab);

  gemm_kernel<1><<<dim3(16, 32), 256, 0, stream>>>(ab, woT, d_out, nullptr, nullptr, 4096, 2048, 2048);
}

// Round 10
// 258.756 us; speedup vs baseline: 1.3329x; 1.3329x over previous
//
#include <hip/hip_runtime.h>
#include <cstdint>
#include <cstddef>

#define T_SEQ 2048
#define DMODEL 2048
#define HQ 16
#define HKV 4
#define HD 128

typedef __attribute__((ext_vector_type(4))) float f32x4;
typedef __attribute__((ext_vector_type(8))) short bf16x8;
typedef __attribute__((ext_vector_type(4))) short short4v;
typedef __attribute__((ext_vector_type(2))) short short2v;
typedef __attribute__((ext_vector_type(4))) unsigned uint4v;

__device__ __forceinline__ short f2bf(float f) {
  unsigned u = __builtin_bit_cast(unsigned, f);
  u = (u + 0x7FFFu + ((u >> 16) & 1u)) >> 16;
  return (short)u;
}
__device__ __forceinline__ float bf2f(short s) {
  unsigned u = ((unsigned)(unsigned short)s) << 16;
  return __builtin_bit_cast(float, u);
}
// pack hi16(a) | hi16(b)<<16 (bf16 truncation) in ONE v_perm_b32
__device__ __forceinline__ unsigned pk_hi16(float a, float b) {
  return __builtin_amdgcn_perm(__builtin_bit_cast(unsigned, b),
                               __builtin_bit_cast(unsigned, a), 0x07060302u);
}

__device__ __forceinline__ void g2lds16(const void* g, void* l) {
  __builtin_amdgcn_global_load_lds(
      (const __attribute__((address_space(1))) void*)g,
      (__attribute__((address_space(3))) void*)l, 16, 0, 0);
}

// ---------------- convert f32 -> bf16 ----------------
__global__ void cvt_kernel(const float* __restrict__ src, short* __restrict__ dst, int n) {
  int idx = blockIdx.x * 256 + threadIdx.x;
  int i = idx * 4;
  if (i >= n) return;
  float4 v = *(const float4*)(src + i);
  short4v o;
  o[0] = f2bf(v.x); o[1] = f2bf(v.y); o[2] = f2bf(v.z); o[3] = f2bf(v.w);
  *(short4v*)(dst + i) = o;
}

// ---------------- transpose + convert: src [R][C] f32 -> dst [C][R] bf16 ----------------
__global__ void transpose_cvt(const float* __restrict__ src, short* __restrict__ dst, int R, int C) {
  __shared__ float tile[32][33];
  int c0 = blockIdx.x * 32, r0 = blockIdx.y * 32;
  int tx = threadIdx.x, ty = threadIdx.y;
  #pragma unroll
  for (int i = 0; i < 32; i += 8)
    tile[ty + i][tx] = src[(size_t)(r0 + ty + i) * C + c0 + tx];
  __syncthreads();
  #pragma unroll
  for (int i = 0; i < 32; i += 8)
    dst[(size_t)(c0 + ty + i) * R + r0 + tx] = f2bf(tile[tx][ty + i]);
}

// ---------------- GEMM: C = A[M][K] * B[K][N], BT is B transposed [N][K] ----------------
template <int MODE>
__global__ __launch_bounds__(256, 2) void gemm_kernel(
    const short* __restrict__ A, const short* __restrict__ BT,
    void* __restrict__ C0, void* __restrict__ C1, void* __restrict__ C2,
    int M, int N, int K)
{
  __shared__ short As[128 * 32];
  __shared__ short Bs[128 * 32];
  const int tid = threadIdx.x;
  const int lane = tid & 63, w = tid >> 6;
  const int l15 = lane & 15, g = lane >> 4;
  const int m0 = blockIdx.y * 128, n0 = blockIdx.x * 128;
  const int wm = (w >> 1) * 64, wn = (w & 1) * 64;

  f32x4 acc[4][4] = {};

  for (int k0 = 0; k0 < K; k0 += 32) {
    __syncthreads();
    #pragma unroll
    for (int call = 0; call < 2; call++) {
      int tau = call * 256 + tid;
      int row = tau >> 2, c = tau & 3;
      int swz = (row & 3) ^ ((row >> 2) & 3);
      g2lds16(A + (size_t)(m0 + row) * K + k0 + ((c ^ swz) << 3),
              (char*)As + call * 4096 + w * 1024);
      g2lds16(BT + (size_t)(n0 + row) * K + k0 + ((c ^ swz) << 3),
              (char*)Bs + call * 4096 + w * 1024);
    }
    __syncthreads();
    bf16x8 af[4], bfr[4];
    #pragma unroll
    for (int mi = 0; mi < 4; mi++) {
      int row = wm + mi * 16 + l15;
      int ch = g ^ ((row & 3) ^ ((row >> 2) & 3));
      af[mi] = *(const bf16x8*)(As + row * 32 + ch * 8);
    }
    #pragma unroll
    for (int ni = 0; ni < 4; ni++) {
      int row = wn + ni * 16 + l15;
      int ch = g ^ ((row & 3) ^ ((row >> 2) & 3));
      bfr[ni] = *(const bf16x8*)(Bs + row * 32 + ch * 8);
    }
    #pragma unroll
    for (int mi = 0; mi < 4; mi++)
      #pragma unroll
      for (int ni = 0; ni < 4; ni++)
        acc[mi][ni] = __builtin_amdgcn_mfma_f32_16x16x32_bf16(af[mi], bfr[ni], acc[mi][ni], 0, 0, 0);
  }

  if (MODE == 1) {
    float* C = (float*)C0;
    #pragma unroll
    for (int mi = 0; mi < 4; mi++)
      #pragma unroll
      for (int r = 0; r < 4; r++) {
        int m = m0 + wm + mi * 16 + g * 4 + r;
        #pragma unroll
        for (int ni = 0; ni < 4; ni++)
          C[(size_t)m * N + n0 + wn + ni * 16 + l15] = acc[mi][ni][r];
      }
  } else {
    short* Cb; int ldc, nc;
    if (MODE == 0) { Cb = (short*)C0; ldc = N; nc = n0; }
    else {
      if (n0 < 2048)      { Cb = (short*)C0; ldc = 2048; nc = n0; }
      else if (n0 < 2560) { Cb = (short*)C1; ldc = 512;  nc = n0 - 2048; }
      else                { Cb = (short*)C2; ldc = 512;  nc = n0 - 2560; }
    }
    #pragma unroll
    for (int mi = 0; mi < 4; mi++)
      #pragma unroll
      for (int r = 0; r < 4; r++) {
        int m = m0 + wm + mi * 16 + g * 4 + r;
        #pragma unroll
        for (int ni = 0; ni < 4; ni++)
          Cb[(size_t)m * ldc + nc + wn + ni * 16 + l15] = f2bf(acc[mi][ni][r]);
      }
  }
}

// ---------------- RoPE in-place on [B*T][NH][128] bf16 ----------------
__global__ void rope_kernel(short* __restrict__ buf, int NH, float scale, int npairs) {
  int idx = blockIdx.x * 256 + threadIdx.x;
  if (idx >= npairs) return;
  int i = idx & 63;
  int th = idx >> 6;
  int t = (th / NH) % T_SEQ;
  size_t base = (size_t)th * 128;
  float invf = exp2f(-(float)i * 0.20762050593046014f);
  float theta = (float)t * invf;
  float sn, cs;
  sincosf(theta, &sn, &cs);
  float a = bf2f(buf[base + i]);
  float b = bf2f(buf[base + 64 + i]);
  buf[base + i]      = f2bf((a * cs - b * sn) * scale);
  buf[base + 64 + i] = f2bf((b * cs + a * sn) * scale);
}

// ---------------- Flash attention (causal, GQA), swapped-operand MFMA ----------------
// 256 thr / 4 waves, 32 q-rows per wave (qc=2): K/V LDS fragments amortized over
// 2x q-rows. __launch_bounds__(256,2): VGPR cap 128 (kernel ~112, NO spill —
// empirical law: cap = 256/N). Residency: LDS 48KB -> 3 blocks/CU; grid 768
// fills it exactly. qti>=8 blocks split kv 2-way (interleaved) -> partials.
__global__ __launch_bounds__(256, 2) void attn_kernel(
    const short* __restrict__ qg, const short* __restrict__ kg,
    const short* __restrict__ vg, short* __restrict__ og,
    short* __restrict__ pOn, float2* __restrict__ ml)
{
  __shared__ short Ks[2][64 * 128];  // 32 KB
  __shared__ short Vt[128 * 64];     // 16 KB
  const int tid = threadIdx.x;
  const int lane = tid & 63, w = tid >> 6;          // 4 waves
  const int l15 = lane & 15, g = lane >> 4;
  const int b = blockIdx.z;
  const int bx = blockIdx.x;                         // 0..23
  const bool split = bx < 16;
  const int qti = split ? (8 + (bx >> 1)) : (bx - 16);
  const int hf = split ? (bx & 1) : 0;
  const int tstep = split ? 2 : 1;
  const int qt0 = qti * 128;
  const int h = blockIdx.y, hk = h >> 2;
  const int qw0 = qt0 + w * 32;                     // 32 q-rows per wave

  // Q fragments: [qc][ks], lane holds Q[q=qw0+qc*16+l15][d=(ks*4+g)*8 ..+7]
  bf16x8 qf[2][4];
  #pragma unroll
  for (int qc = 0; qc < 2; qc++) {
    size_t t = (size_t)b * T_SEQ + qw0 + qc * 16 + l15;
    const short* qp = qg + (t * HQ + h) * HD;
    #pragma unroll
    for (int ks = 0; ks < 4; ks++)
      qf[qc][ks] = *(const bf16x8*)(qp + ks * 32 + g * 8);
  }

  f32x4 of[2][8] = {};               // O^T acc [qc][dc]: d=dc*16+4g+r, q=l15
  float m2[2] = {-INFINITY, -INFINITY};
  float ls[2] = {0.f, 0.f};          // per-lane partials (reduced at epilogue)

  const short* kbase = kg + ((size_t)b * T_SEQ * HKV + hk) * HD;
  const short* vbase = vg + ((size_t)b * T_SEQ * HKV + hk) * HD;
  const int ti = tid & 15;
  const int kv4 = ti * 4, d8s = (tid >> 4) * 8;
  // stored position of kv=4*ti (P k-order); kv4..kv4+3 -> pbase..pbase+3
  const int pbase = (ti >> 3) * 32 + (ti & 3) * 8 + ((ti >> 2) & 1) * 4;
  const int ntAll = 2 * qti + 2;     // kv tiles of 64 (absolute count)

  bf16x8 vr[4];

  auto stageK = [&](int t, int nb) {
    #pragma unroll
    for (int call = 0; call < 4; call++) {
      int tau = call * 256 + tid;
      int kv = tau >> 4, c = tau & 15;
      g2lds16(kbase + (size_t)(t * 64 + kv) * (HKV * HD) + ((c ^ (kv & 7)) << 3),
              (char*)Ks[nb] + call * 4096 + w * 1024);
    }
  };
  auto loadV = [&](int t) {
    #pragma unroll
    for (int i = 0; i < 4; i++)
      vr[i] = *(const bf16x8*)(vbase + (size_t)(t * 64 + kv4 + i) * (HKV * HD) + d8s);
  };
  auto writeV = [&]() {
    #pragma unroll
    for (int e = 0; e < 8; e++) {
      short4v t4;
      t4[0] = vr[0][e]; t4[1] = vr[1][e]; t4[2] = vr[2][e]; t4[3] = vr[3][e];
      *(short4v*)(&Vt[(d8s + e) * 64 + (pbase ^ (e << 3))]) = t4;
    }
  };

  // prologue: first tile (index hf) into buffer 0
  stageK(hf, 0);
  loadV(hf);
  __syncthreads();                    // K staged; vr valid
  writeV();
  __syncthreads();                    // Vt visible

  int buf = 0;
  for (int t = hf; t < ntAll; t += tstep) {
    const int kv0 = t * 64;
    const int tn = t + tstep;
    const bool haveNext = (tn < ntAll);
    if (haveNext) { loadV(tn); stageK(tn, buf ^ 1); }

    if (kv0 <= qw0 + 31) {
      const short* Kc = Ks[buf];
      f32x4 sacc[4][2] = {};
      __builtin_amdgcn_s_setprio(1);
      #pragma unroll
      for (int ks = 0; ks < 4; ks++) {
        bf16x8 kf[4];
        #pragma unroll
        for (int kt = 0; kt < 4; kt++) {
          int row = kt * 16 + l15;
          int ch = (ks * 4 + g) ^ (row & 7);
          kf[kt] = *(const bf16x8*)(Kc + row * 128 + ch * 8);
        }
        #pragma unroll
        for (int kt = 0; kt < 4; kt++)
          #pragma unroll
          for (int qc = 0; qc < 2; qc++)
            sacc[kt][qc] = __builtin_amdgcn_mfma_f32_16x16x32_bf16(kf[kt], qf[qc][ks], sacc[kt][qc], 0, 0, 0);
      }
      __builtin_amdgcn_s_setprio(0);
      const bool needmask = (kv0 + 63) > qw0;
      bf16x8 pb[2][2];                 // [ktw][qc]
      #pragma unroll
      for (int qc = 0; qc < 2; qc++) {
        int qpos = qw0 + qc * 16 + l15;
        float vmax = -INFINITY;
        #pragma unroll
        for (int kt = 0; kt < 4; kt++)
          #pragma unroll
          for (int r = 0; r < 4; r++) {
            int kvpos = kv0 + kt * 16 + g * 4 + r;
            float sv = sacc[kt][qc][r];
            if (needmask && kvpos > qpos) sv = -INFINITY;
            sacc[kt][qc][r] = sv;
            vmax = fmaxf(vmax, sv);
          }
        vmax = fmaxf(vmax, __shfl_xor(vmax, 16));
        vmax = fmaxf(vmax, __shfl_xor(vmax, 32));
        if (!__all(vmax <= m2[qc] + 8.0f)) {   // defer-max (T13)
          float mnew = fmaxf(m2[qc], vmax);
          float resc = exp2f(m2[qc] - mnew);
          m2[qc] = mnew;
          ls[qc] *= resc;                       // per-lane partial; resc row-uniform
          #pragma unroll
          for (int dc = 0; dc < 8; dc++) of[qc][dc] *= resc;
        }
        float mref = m2[qc];
        #pragma unroll
        for (int kt = 0; kt < 4; kt++)
          #pragma unroll
          for (int r = 0; r < 4; r++) {
            float p = exp2f(sacc[kt][qc][r] - mref);
            sacc[kt][qc][r] = p;
            ls[qc] += p;                        // deferred: no per-tile shuffles
          }
        // pack P into stored k-order
        #pragma unroll
        for (int ktw = 0; ktw < 2; ktw++) {
          uint4v pw;
          pw[0] = pk_hi16(sacc[2 * ktw][qc][0], sacc[2 * ktw][qc][1]);
          pw[1] = pk_hi16(sacc[2 * ktw][qc][2], sacc[2 * ktw][qc][3]);
          pw[2] = pk_hi16(sacc[2 * ktw + 1][qc][0], sacc[2 * ktw + 1][qc][1]);
          pw[3] = pk_hi16(sacc[2 * ktw + 1][qc][2], sacc[2 * ktw + 1][qc][3]);
          pb[ktw][qc] = __builtin_bit_cast(bf16x8, pw);
        }
      }
      // O^T += V^T * P : one swizzled ds_read_b128 per fragment, shared by qc pair
      __builtin_amdgcn_s_setprio(1);
      #pragma unroll
      for (int ktw = 0; ktw < 2; ktw++)
        #pragma unroll
        for (int dc = 0; dc < 8; dc++) {
          int row = dc * 16 + l15;
          bf16x8 vf = *(const bf16x8*)(&Vt[row * 64 + ((ktw * 32 + g * 8) ^ ((l15 & 7) << 3))]);
          #pragma unroll
          for (int qc = 0; qc < 2; qc++)
            of[qc][dc] = __builtin_amdgcn_mfma_f32_16x16x32_bf16(vf, pb[ktw][qc], of[qc][dc], 0, 0, 0);
        }
      __builtin_amdgcn_s_setprio(0);
    }

    __syncthreads();                 // reads of Vt/Ks[buf] done; prefetch drained
    if (haveNext) writeV();
    __syncthreads();                 // Vt(next) visible
    buf ^= 1;
  }

  // epilogue: reduce ls across g-lanes, then store
  #pragma unroll
  for (int qc = 0; qc < 2; qc++) {
    float lss = ls[qc];
    lss += __shfl_xor(lss, 16);
    lss += __shfl_xor(lss, 32);
    float inv = 1.0f / lss;
    if (!split) {
      size_t t = (size_t)b * T_SEQ + qw0 + qc * 16 + l15;
      short* op = og + (t * HQ + h) * HD;
      #pragma unroll
      for (int dc = 0; dc < 8; dc++) {
        short4v o;
        #pragma unroll
        for (int r = 0; r < 4; r++) o[r] = f2bf(of[qc][dc][r] * inv);
        *(short4v*)(op + dc * 16 + g * 4) = o;
      }
    } else {
      size_t row = ((size_t)((b * 16 + h) * 2 + hf)) * 1024 + (qw0 - 1024) + qc * 16 + l15;
      short* op = pOn + row * 128;
      #pragma unroll
      for (int dc = 0; dc < 8; dc++) {
        short4v o;
        #pragma unroll
        for (int r = 0; r < 4; r++) o[r] = f2bf(of[qc][dc][r] * inv);
        *(short4v*)(op + dc * 16 + g * 4) = o;
      }
      if (g == 0) {
        float2 st; st.x = m2[qc]; st.y = lss;
        ml[row] = st;
      }
    }
  }
}

// ---------------- combine split-KV partials (q rows 1024..2047) -> ab ----------------
__global__ void combine_kernel(const short* __restrict__ pOn, const float2* __restrict__ ml,
                               short* __restrict__ ab) {
  int idx = blockIdx.x * 256 + threadIdx.x;   // 1,048,576 threads
  int d4 = (idx & 31) * 4;
  int r = idx >> 5;                           // bh*1024 + q'
  int q = r & 1023, bh = r >> 10;             // bh in [0,32)
  size_t row0 = ((size_t)bh * 2) * 1024 + q;
  size_t row1 = row0 + 1024;
  float2 s0 = ml[row0], s1 = ml[row1];
  float M = fmaxf(s0.x, s1.x);
  float w0 = s0.y * exp2f(s0.x - M);
  float w1 = s1.y * exp2f(s1.x - M);
  float inv = 1.0f / (w0 + w1);
  w0 *= inv; w1 *= inv;
  short4v a = *(const short4v*)(pOn + row0 * 128 + d4);
  short4v c = *(const short4v*)(pOn + row1 * 128 + d4);
  short4v o;
  #pragma unroll
  for (int j = 0; j < 4; j++) o[j] = f2bf(w0 * bf2f(a[j]) + w1 * bf2f(c[j]));
  int bb = bh >> 4, hh = bh & 15;
  *(short4v*)(ab + ((size_t)(bb * T_SEQ + 1024 + q) * 16 + hh) * 128 + d4) = o;
}

extern "C" void kernel_launch(void* const* d_in, const int* in_sizes, int n_in,
                              void* d_out, int out_size, void* d_ws, size_t ws_size,
                              hipStream_t stream) {
  (void)in_sizes; (void)n_in; (void)out_size; (void)ws_size;
  const float* x  = (const float*)d_in[0];
  const float* Wq = (const float*)d_in[2];
  const float* Wk = (const float*)d_in[3];
  const float* Wv = (const float*)d_in[4];
  const float* Wo = (const float*)d_in[5];

  char* ws = (char*)d_ws;
  // phase-1 overlays (dead after QKV GEMM):
  short*  xb   = (short*)(ws);                   // [0,16M)
  short*  wall = (short*)(ws + 16777216);        // [16M,29.4M) WqT|WkT|WvT
  short*  wkT  = wall + (size_t)2048 * 2048;
  short*  wvT  = wall + (size_t)2560 * 2048;
  // phase-2 overlays (attn partials; reuse xb/wall space):
  short*  pOn  = (short*)(ws);                   // [0,16M)
  float2* ml   = (float2*)(ws + 16777216);       // [16M,16.5M)
  // persistent:
  short*  woT  = (short*)(ws + 29360128);        // 8 MB
  short*  qb   = (short*)(ws + 37748736);        // 16 MB [B,T,HQ,128]
  short*  kb   = (short*)(ws + 54525952);        // 4 MB  [B,T,HKV,128]
  short*  vb   = (short*)(ws + 58720256);        // 4 MB  [B,T,HKV,128]
  short*  ab   = (short*)(ws + 62914560);        // 16 MB [4096][2048]

  const float MULT = 0.08838834764831845f;
  const float LOG2E = 1.4426950408889634f;
  const float QSCALE = MULT * LOG2E;

  dim3 tb(32, 8);
  cvt_kernel<<<8192, 256, 0, stream>>>(x, xb, 8388608);
  transpose_cvt<<<dim3(64, 64), tb, 0, stream>>>(Wq, wall, 2048, 2048);
  transpose_cvt<<<dim3(16, 64), tb, 0, stream>>>(Wk, wkT, 2048, 512);
  transpose_cvt<<<dim3(16, 64), tb, 0, stream>>>(Wv, wvT, 2048, 512);
  transpose_cvt<<<dim3(64, 64), tb, 0, stream>>>(Wo, woT, 2048, 2048);

  // fused QKV projection: [4096][2048] x [2048][3072] -> qb|kb|vb
  gemm_kernel<2><<<dim3(24, 32), 256, 0, stream>>>(xb, wall, qb, kb, vb, 4096, 3072, 2048);

  rope_kernel<<<16384, 256, 0, stream>>>(qb, HQ, QSCALE, 4194304);
  rope_kernel<<<4096, 256, 0, stream>>>(kb, HKV, 1.0f, 1048576);

  attn_kernel<<<dim3(24, 16, 2), 256, 0, stream>>>(qb, kb, vb, ab, pOn, ml);
  combine_kernel<<<4096, 256, 0, stream>>>(pOn, ml, ab);

  gemm_kernel<1><<<dim3(16, 32), 256, 0, stream>>>(ab, woT, d_out, nullptr, nullptr, 4096, 2048, 2048);
}

// Round 11
// 224.968 us; speedup vs baseline: 1.5331x; 1.1502x over previous
//
#include <hip/hip_runtime.h>
#include <cstdint>
#include <cstddef>

#define T_SEQ 2048
#define DMODEL 2048
#define HQ 16
#define HKV 4
#define HD 128

typedef __attribute__((ext_vector_type(4))) float f32x4;
typedef __attribute__((ext_vector_type(8))) short bf16x8;
typedef __attribute__((ext_vector_type(4))) short short4v;
typedef __attribute__((ext_vector_type(2))) short short2v;
typedef __attribute__((ext_vector_type(4))) unsigned uint4v;

__device__ __forceinline__ short f2bf(float f) {
  unsigned u = __builtin_bit_cast(unsigned, f);
  u = (u + 0x7FFFu + ((u >> 16) & 1u)) >> 16;
  return (short)u;
}
__device__ __forceinline__ float bf2f(short s) {
  unsigned u = ((unsigned)(unsigned short)s) << 16;
  return __builtin_bit_cast(float, u);
}
// pack hi16(a) | hi16(b)<<16 (bf16 truncation) in ONE v_perm_b32
__device__ __forceinline__ unsigned pk_hi16(float a, float b) {
  return __builtin_amdgcn_perm(__builtin_bit_cast(unsigned, b),
                               __builtin_bit_cast(unsigned, a), 0x07060302u);
}

__device__ __forceinline__ void g2lds16(const void* g, void* l) {
  __builtin_amdgcn_global_load_lds(
      (const __attribute__((address_space(1))) void*)g,
      (__attribute__((address_space(3))) void*)l, 16, 0, 0);
}

// ---------------- convert f32 -> bf16 ----------------
__global__ void cvt_kernel(const float* __restrict__ src, short* __restrict__ dst, int n) {
  int idx = blockIdx.x * 256 + threadIdx.x;
  int i = idx * 4;
  if (i >= n) return;
  float4 v = *(const float4*)(src + i);
  short4v o;
  o[0] = f2bf(v.x); o[1] = f2bf(v.y); o[2] = f2bf(v.z); o[3] = f2bf(v.w);
  *(short4v*)(dst + i) = o;
}

// ---------------- batched transpose+convert: 4 weights in one launch ----------------
// z=0: Wq [2048][2048], z=1: Wk [2048][512], z=2: Wv [2048][512], z=3: Wo [2048][2048]
__global__ void transpose_cvt4(const float* __restrict__ s0, const float* __restrict__ s1,
                               const float* __restrict__ s2, const float* __restrict__ s3,
                               short* __restrict__ d0, short* __restrict__ d1,
                               short* __restrict__ d2, short* __restrict__ d3) {
  __shared__ float tile[32][33];
  const int z = blockIdx.z;
  const float* src = (z == 0) ? s0 : (z == 1) ? s1 : (z == 2) ? s2 : s3;
  short* dst = (z == 0) ? d0 : (z == 1) ? d1 : (z == 2) ? d2 : d3;
  const int C = (z == 1 || z == 2) ? 512 : 2048;
  const int R = 2048;
  int c0 = blockIdx.x * 32, r0 = blockIdx.y * 32;
  if (c0 >= C) return;
  int tx = threadIdx.x, ty = threadIdx.y;
  #pragma unroll
  for (int i = 0; i < 32; i += 8)
    tile[ty + i][tx] = src[(size_t)(r0 + ty + i) * C + c0 + tx];
  __syncthreads();
  #pragma unroll
  for (int i = 0; i < 32; i += 8)
    dst[(size_t)(c0 + ty + i) * R + r0 + tx] = f2bf(tile[tx][ty + i]);
}

// ---------------- GEMM: C = A[M][K] * B[K][N], BT is B transposed [N][K] ----------------
template <int MODE>
__global__ __launch_bounds__(256, 2) void gemm_kernel(
    const short* __restrict__ A, const short* __restrict__ BT,
    void* __restrict__ C0, void* __restrict__ C1, void* __restrict__ C2,
    int M, int N, int K)
{
  __shared__ short As[128 * 32];
  __shared__ short Bs[128 * 32];
  const int tid = threadIdx.x;
  const int lane = tid & 63, w = tid >> 6;
  const int l15 = lane & 15, g = lane >> 4;
  const int m0 = blockIdx.y * 128, n0 = blockIdx.x * 128;
  const int wm = (w >> 1) * 64, wn = (w & 1) * 64;

  f32x4 acc[4][4] = {};

  for (int k0 = 0; k0 < K; k0 += 32) {
    __syncthreads();
    #pragma unroll
    for (int call = 0; call < 2; call++) {
      int tau = call * 256 + tid;
      int row = tau >> 2, c = tau & 3;
      int swz = (row & 3) ^ ((row >> 2) & 3);
      g2lds16(A + (size_t)(m0 + row) * K + k0 + ((c ^ swz) << 3),
              (char*)As + call * 4096 + w * 1024);
      g2lds16(BT + (size_t)(n0 + row) * K + k0 + ((c ^ swz) << 3),
              (char*)Bs + call * 4096 + w * 1024);
    }
    __syncthreads();
    bf16x8 af[4], bfr[4];
    #pragma unroll
    for (int mi = 0; mi < 4; mi++) {
      int row = wm + mi * 16 + l15;
      int ch = g ^ ((row & 3) ^ ((row >> 2) & 3));
      af[mi] = *(const bf16x8*)(As + row * 32 + ch * 8);
    }
    #pragma unroll
    for (int ni = 0; ni < 4; ni++) {
      int row = wn + ni * 16 + l15;
      int ch = g ^ ((row & 3) ^ ((row >> 2) & 3));
      bfr[ni] = *(const bf16x8*)(Bs + row * 32 + ch * 8);
    }
    #pragma unroll
    for (int mi = 0; mi < 4; mi++)
      #pragma unroll
      for (int ni = 0; ni < 4; ni++)
        acc[mi][ni] = __builtin_amdgcn_mfma_f32_16x16x32_bf16(af[mi], bfr[ni], acc[mi][ni], 0, 0, 0);
  }

  if (MODE == 1) {
    float* C = (float*)C0;
    #pragma unroll
    for (int mi = 0; mi < 4; mi++)
      #pragma unroll
      for (int r = 0; r < 4; r++) {
        int m = m0 + wm + mi * 16 + g * 4 + r;
        #pragma unroll
        for (int ni = 0; ni < 4; ni++)
          C[(size_t)m * N + n0 + wn + ni * 16 + l15] = acc[mi][ni][r];
      }
  } else {
    short* Cb; int ldc, nc;
    if (MODE == 0) { Cb = (short*)C0; ldc = N; nc = n0; }
    else {
      if (n0 < 2048)      { Cb = (short*)C0; ldc = 2048; nc = n0; }
      else if (n0 < 2560) { Cb = (short*)C1; ldc = 512;  nc = n0 - 2048; }
      else                { Cb = (short*)C2; ldc = 512;  nc = n0 - 2560; }
    }
    #pragma unroll
    for (int mi = 0; mi < 4; mi++)
      #pragma unroll
      for (int r = 0; r < 4; r++) {
        int m = m0 + wm + mi * 16 + g * 4 + r;
        #pragma unroll
        for (int ni = 0; ni < 4; ni++)
          Cb[(size_t)m * ldc + nc + wn + ni * 16 + l15] = f2bf(acc[mi][ni][r]);
      }
  }
}

// ---------------- RoPE, q and k in ONE launch (block-aligned split) ----------------
// idx < 4194304 -> q (NH=16, scale=qscale); else -> k (NH=4, scale=1).
__global__ void rope_all(short* __restrict__ qbuf, short* __restrict__ kbuf, float qscale) {
  int idx = blockIdx.x * 256 + threadIdx.x;
  short* buf; int NH; float scale;
  if (idx < 4194304) { buf = qbuf; NH = HQ; scale = qscale; }
  else               { buf = kbuf; NH = HKV; scale = 1.0f; idx -= 4194304; }
  int i = idx & 63;
  int th = idx >> 6;
  int t = (th / NH) % T_SEQ;
  size_t base = (size_t)th * 128;
  float invf = exp2f(-(float)i * 0.20762050593046014f);
  float theta = (float)t * invf;
  float sn, cs;
  sincosf(theta, &sn, &cs);
  float a = bf2f(buf[base + i]);
  float b = bf2f(buf[base + 64 + i]);
  buf[base + i]      = f2bf((a * cs - b * sn) * scale);
  buf[base + 64 + i] = f2bf((b * cs + a * sn) * scale);
}

// ---------------- Flash attention (causal, GQA), swapped-operand MFMA ----------------
// ROUND-5 PROVEN CONFIG (91 us): 512 threads = 8 waves, 16 q-rows per wave,
// kv tile 64. K double-buffered via global_load_lds (32 KB); V^T single-buffered
// (16 KB) with T14 split staging, columns pre-permuted to P's register k-order +
// XOR swizzle. Two barriers per tile. Grid (16,16,2), causal pairing balance.
__global__ __launch_bounds__(512, 4) void attn_kernel(
    const short* __restrict__ qg, const short* __restrict__ kg,
    const short* __restrict__ vg, short* __restrict__ og)
{
  __shared__ short Ks[2][64 * 128];  // 32 KB
  __shared__ short Vt[128 * 64];     // 16 KB
  const int tid = threadIdx.x;
  const int lane = tid & 63, w = tid >> 6;          // 8 waves
  const int l15 = lane & 15, g = lane >> 4;
  const int b = blockIdx.z;
  const int qti = b ? (15 - (int)blockIdx.x) : (int)blockIdx.x;  // causal pairing balance
  const int qt0 = qti * 128;
  const int h = blockIdx.y, hk = h >> 2;
  const int qw0 = qt0 + w * 16;                     // 16 q-rows per wave

  // Q fragments: lane holds Q[q=qw0+l15][d=(ks*4+g)*8 ..+7]
  bf16x8 qf[4];
  {
    size_t t = (size_t)b * T_SEQ + qw0 + l15;
    const short* qp = qg + (t * HQ + h) * HD;
    #pragma unroll
    for (int ks = 0; ks < 4; ks++)
      qf[ks] = *(const bf16x8*)(qp + ks * 32 + g * 8);
  }

  f32x4 of[8] = {};                  // O^T acc [dc]: d=dc*16+4g+r, q=l15
  float m2 = -INFINITY;
  float ls = 0.f;

  const short* kbase = kg + ((size_t)b * T_SEQ * HKV + hk) * HD;
  const short* vbase = vg + ((size_t)b * T_SEQ * HKV + hk) * HD;

  // V staging assignment (512 threads): 2 kv rows x 8 d each
  const int kv2 = (tid & 31) * 2;
  const int d8s = (tid >> 5) * 8;
  // stored position of kv (P k-order): p = (kv>>5)*32 + ((kv&15)>>2)*8 + ((kv>>4)&1)*4 + (kv&3)
  const int p0 = (kv2 >> 5) * 32 + ((kv2 & 15) >> 2) * 8 + ((kv2 >> 4) & 1) * 4 + (kv2 & 3);
  const int nt = (qt0 + 128) >> 6;

  bf16x8 vr[2];

  auto stageK = [&](int t, int nb) {
    #pragma unroll
    for (int call = 0; call < 2; call++) {
      int tau = call * 512 + tid;
      int kv = tau >> 4, c = tau & 15;
      g2lds16(kbase + (size_t)(t * 64 + kv) * (HKV * HD) + ((c ^ (kv & 7)) << 3),
              (char*)Ks[nb] + call * 8192 + w * 1024);
    }
  };
  auto loadV = [&](int t) {
    const short* vp = vbase + (size_t)(t * 64 + kv2) * (HKV * HD) + d8s;
    vr[0] = *(const bf16x8*)(vp);
    vr[1] = *(const bf16x8*)(vp + HKV * HD);
  };
  auto writeV = [&]() {
    #pragma unroll
    for (int e = 0; e < 8; e++) {
      int row = d8s + e;
      int addr = row * 64 + (((p0 >> 3) ^ e) << 3) + (p0 & 7);
      short2v t2; t2[0] = vr[0][e]; t2[1] = vr[1][e];
      *(short2v*)(&Vt[addr]) = t2;
    }
  };

  // prologue
  stageK(0, 0);
  loadV(0);
  __syncthreads();                    // K(0) staged (vmcnt drained)
  writeV();
  __syncthreads();                    // Vt(0) visible

  int cur = 0;
  for (int t = 0; t < nt; t++) {
    const int kv0 = t * 64;
    const bool haveNext = (t + 1 < nt);
    if (haveNext) { loadV(t + 1); stageK(t + 1, cur ^ 1); }

    if (kv0 <= qw0 + 15) {
      const short* Kc = Ks[cur];
      f32x4 sacc[4] = {};
      __builtin_amdgcn_s_setprio(1);
      #pragma unroll
      for (int ks = 0; ks < 4; ks++) {
        bf16x8 kf[4];
        #pragma unroll
        for (int kt = 0; kt < 4; kt++) {
          int row = kt * 16 + l15;
          int ch = (ks * 4 + g) ^ (row & 7);
          kf[kt] = *(const bf16x8*)(Kc + row * 128 + ch * 8);
        }
        #pragma unroll
        for (int kt = 0; kt < 4; kt++)
          sacc[kt] = __builtin_amdgcn_mfma_f32_16x16x32_bf16(kf[kt], qf[ks], sacc[kt], 0, 0, 0);
      }
      __builtin_amdgcn_s_setprio(0);
      const bool needmask = (kv0 + 63) > qw0;
      const int qpos = qw0 + l15;
      float vmax = -INFINITY;
      #pragma unroll
      for (int kt = 0; kt < 4; kt++)
        #pragma unroll
        for (int r = 0; r < 4; r++) {
          int kvpos = kv0 + kt * 16 + g * 4 + r;
          float sv = sacc[kt][r];
          if (needmask && kvpos > qpos) sv = -INFINITY;
          sacc[kt][r] = sv;
          vmax = fmaxf(vmax, sv);
        }
      vmax = fmaxf(vmax, __shfl_xor(vmax, 16));
      vmax = fmaxf(vmax, __shfl_xor(vmax, 32));
      if (!__all(vmax <= m2 + 8.0f)) {   // defer-max (T13)
        float mnew = fmaxf(m2, vmax);
        float resc = exp2f(m2 - mnew);
        m2 = mnew;
        ls *= resc;
        #pragma unroll
        for (int dc = 0; dc < 8; dc++) of[dc] *= resc;
      }
      float lsum = 0.f;
      #pragma unroll
      for (int kt = 0; kt < 4; kt++)
        #pragma unroll
        for (int r = 0; r < 4; r++) {
          float p = exp2f(sacc[kt][r] - m2);
          sacc[kt][r] = p;
          lsum += p;
        }
      lsum += __shfl_xor(lsum, 16);
      lsum += __shfl_xor(lsum, 32);
      ls += lsum;
      // pack P into stored k-order: frag ktw: j<4 -> sacc[2ktw], j>=4 -> sacc[2ktw+1]
      bf16x8 pb[2];
      #pragma unroll
      for (int ktw = 0; ktw < 2; ktw++) {
        uint4v pw;
        pw[0] = pk_hi16(sacc[2 * ktw][0], sacc[2 * ktw][1]);
        pw[1] = pk_hi16(sacc[2 * ktw][2], sacc[2 * ktw][3]);
        pw[2] = pk_hi16(sacc[2 * ktw + 1][0], sacc[2 * ktw + 1][1]);
        pw[3] = pk_hi16(sacc[2 * ktw + 1][2], sacc[2 * ktw + 1][3]);
        pb[ktw] = __builtin_bit_cast(bf16x8, pw);
      }
      // O^T += V^T * P : one swizzled ds_read_b128 per fragment
      __builtin_amdgcn_s_setprio(1);
      #pragma unroll
      for (int ktw = 0; ktw < 2; ktw++)
        #pragma unroll
        for (int dc = 0; dc < 8; dc++) {
          int row = dc * 16 + l15;
          bf16x8 vf = *(const bf16x8*)(&Vt[row * 64 + ((ktw * 32 + g * 8) ^ ((l15 & 7) << 3))]);
          of[dc] = __builtin_amdgcn_mfma_f32_16x16x32_bf16(vf, pb[ktw], of[dc], 0, 0, 0);
        }
      __builtin_amdgcn_s_setprio(0);
    }

    __syncthreads();                 // all waves done with Vt / Ks[cur]; prefetch drained
    if (haveNext) writeV();
    __syncthreads();                 // Vt(t+1) visible
    cur ^= 1;
  }

  // epilogue: normalize and store O (lane: q=l15, d=dc*16+4g+r)
  {
    float inv = 1.0f / ls;
    size_t t = (size_t)b * T_SEQ + qw0 + l15;
    short* op = og + (t * HQ + h) * HD;
    #pragma unroll
    for (int dc = 0; dc < 8; dc++) {
      short4v o;
      #pragma unroll
      for (int r = 0; r < 4; r++) o[r] = f2bf(of[dc][r] * inv);
      *(short4v*)(op + dc * 16 + g * 4) = o;
    }
  }
}

extern "C" void kernel_launch(void* const* d_in, const int* in_sizes, int n_in,
                              void* d_out, int out_size, void* d_ws, size_t ws_size,
                              hipStream_t stream) {
  (void)in_sizes; (void)n_in; (void)out_size; (void)ws_size;
  const float* x  = (const float*)d_in[0];
  const float* Wq = (const float*)d_in[2];
  const float* Wk = (const float*)d_in[3];
  const float* Wv = (const float*)d_in[4];
  const float* Wo = (const float*)d_in[5];

  char* ws = (char*)d_ws;
  short* xb   = (short*)(ws);                    // 16 MB   [4096][2048]
  short* wall = (short*)(ws + 16777216);         // 12.6 MB [3072][2048] = WqT|WkT|WvT
  short* wkT  = wall + (size_t)2048 * 2048;
  short* wvT  = wall + (size_t)2560 * 2048;
  short* woT  = (short*)(ws + 29360128);         // 8 MB    [2048][2048]
  short* qb   = (short*)(ws + 37748736);         // 16 MB   [B,T,HQ,128]
  short* kb   = (short*)(ws + 54525952);         // 4 MB    [B,T,HKV,128]
  short* vb   = (short*)(ws + 58720256);         // 4 MB    [B,T,HKV,128]
  short* ab   = (short*)(ws + 62914560);         // 16 MB   [4096][2048]

  const float MULT = 0.08838834764831845f;
  const float LOG2E = 1.4426950408889634f;
  const float QSCALE = MULT * LOG2E;

  dim3 tb(32, 8);
  cvt_kernel<<<8192, 256, 0, stream>>>(x, xb, 8388608);
  transpose_cvt4<<<dim3(64, 64, 4), tb, 0, stream>>>(Wq, Wk, Wv, Wo, wall, wkT, wvT, woT);

  // fused QKV projection: [4096][2048] x [2048][3072] -> qb|kb|vb
  gemm_kernel<2><<<dim3(24, 32), 256, 0, stream>>>(xb, wall, qb, kb, vb, 4096, 3072, 2048);

  rope_all<<<20480, 256, 0, stream>>>(qb, kb, QSCALE);

  attn_kernel<<<dim3(16, 16, 2), 512, 0, stream>>>(qb, kb, vb, ab);

  gemm_kernel<1><<<dim3(16, 32), 256, 0, stream>>>(ab, woT, d_out, nullptr, nullptr, 4096, 2048, 2048);
}